// Round 1
// baseline (505.157 us; speedup 1.0000x reference)
//
#include <hip/hip_runtime.h>
#include <hip/hip_bf16.h>
#include <stdint.h>
#include <math.h>

typedef __bf16 bf16_t;
typedef __bf16 bf16x8 __attribute__((ext_vector_type(8)));
typedef __bf16 bf16x4 __attribute__((ext_vector_type(4)));
typedef float  f32x4  __attribute__((ext_vector_type(4)));

// Problem constants: B=16,H=64,W=80,C=256; GH=8,GW=10; heads=8,DH=32; INNER=1024
// partition: window w=(b*8+h2)*8+w2 (h2=h%8,w2=w%8), token n=gh*10+gw (gh=h/8,gw=w/8)

__device__ __forceinline__ int map_p_to_g(int p) {
    // partition row -> original row
    int w = p / 80, n = p - w * 80;
    int b  = w >> 6, h2 = (w >> 3) & 7, w2 = w & 7;
    int gh = n / 10, gw = n - gh * 10;
    return b * 5120 + (gh * 8 + h2) * 80 + (gw * 8 + w2);
}

// ---------------- weight convert+transpose: fp32 [K][N] -> bf16 [N][K] ----------------
__global__ __launch_bounds__(256) void wconv_k(const float* __restrict__ in,
                                               bf16_t* __restrict__ out, int N, int K)
{
    int i = blockIdx.x * 256 + threadIdx.x;   // grid sized exactly N*K/256
    int n = i / K, k = i - n * K;
    out[i] = (bf16_t)in[(size_t)k * N + n];
}

// ---------------- LayerNorm (one wave per row), optional partition permute ----------------
template <int PERM>
__global__ __launch_bounds__(256) void ln_k(const float* __restrict__ in,
                                            const float* __restrict__ gg,
                                            const float* __restrict__ bb,
                                            bf16_t* __restrict__ o)
{
    int row  = blockIdx.x * 4 + (threadIdx.x >> 6);
    int lane = threadIdx.x & 63;
    const float4 xv = *(const float4*)(in + (size_t)row * 256 + lane * 4);
    float s = xv.x + xv.y + xv.z + xv.w;
#pragma unroll
    for (int m = 1; m < 64; m <<= 1) s += __shfl_xor(s, m, 64);
    float mean = s * (1.f / 256.f);
    float d0 = xv.x - mean, d1 = xv.y - mean, d2 = xv.z - mean, d3 = xv.w - mean;
    float v = d0 * d0 + d1 * d1 + d2 * d2 + d3 * d3;
#pragma unroll
    for (int m = 1; m < 64; m <<= 1) v += __shfl_xor(v, m, 64);
    float rstd = rsqrtf(v * (1.f / 256.f) + 1e-5f);
    const float4 gv = *(const float4*)(gg + lane * 4);
    const float4 bv = *(const float4*)(bb + lane * 4);
    int orow = row;
    if (PERM) {
        int b = row / 5120, r1 = row - b * 5120;
        int h = r1 / 80, wv = r1 - h * 80;
        int gh = h >> 3, h2 = h & 7, gw = wv >> 3, w2 = wv & 7;
        orow = ((b * 8 + h2) * 8 + w2) * 80 + gh * 10 + gw;
    }
    bf16x4 ov;
    ov[0] = (bf16_t)(d0 * rstd * gv.x + bv.x);
    ov[1] = (bf16_t)(d1 * rstd * gv.y + bv.y);
    ov[2] = (bf16_t)(d2 * rstd * gv.z + bv.z);
    ov[3] = (bf16_t)(d3 * rstd * gv.w + bv.w);
    *(bf16x4*)(o + (size_t)orow * 256 + lane * 4) = ov;
}

// ---------------- tiled bf16 MFMA GEMM: C[81920,N] = A[81920,K] * Bt[N,K]^T ----------------
// 128x128 tile, BK=32, 4 waves (2x2), each wave 64x64 (4x4 frags of 16x16x32).
// EPI: 0 = bf16 out (+bias)   [qkv]
//      1 = fp32 out = x[g] + ls*(acc+bias), grid-reverse row map  [proj]
//      2 = bf16 out = gelu(acc+bias)  [fc1]
//      3 = fp32 out[idx] += ls*(acc+bias)  [fc2, in-place on d_out]
template <int EPI>
__global__ __launch_bounds__(256) void gemm_k(const bf16_t* __restrict__ A,
                                              const bf16_t* __restrict__ Bt,
                                              const float* __restrict__ bias,
                                              const float* __restrict__ xres,
                                              const float* __restrict__ ls,
                                              void* __restrict__ outp,
                                              int N, int K)
{
    __shared__ bf16_t At[128 * 40];   // pad 32->40: 80B row stride, 16B aligned, 2-way banks (free)
    __shared__ bf16_t Bl[128 * 40];
    const int t = threadIdx.x;
    const int wid = t >> 6, lane = t & 63;
    const int wr = wid >> 1, wc = wid & 1;
    const int ln = lane & 15, kg = lane >> 4;
    const int row0 = blockIdx.y * 128;
    const int col0 = blockIdx.x * 128;
    const int srow = t >> 2;          // 0..63
    const int scol = (t & 3) * 8;     // 0,8,16,24

    const f32x4 fz = {0.f, 0.f, 0.f, 0.f};
    f32x4 acc[4][4];
#pragma unroll
    for (int i = 0; i < 4; ++i)
#pragma unroll
        for (int j = 0; j < 4; ++j) acc[i][j] = fz;

    const bf16_t* ga = A + (size_t)(row0 + srow) * K + scol;
    const bf16_t* gb = Bt + (size_t)(col0 + srow) * K + scol;

    for (int k0 = 0; k0 < K; k0 += 32) {
        bf16x8 a0 = *(const bf16x8*)(ga + k0);
        bf16x8 a1 = *(const bf16x8*)(ga + (size_t)64 * K + k0);
        bf16x8 b0 = *(const bf16x8*)(gb + k0);
        bf16x8 b1 = *(const bf16x8*)(gb + (size_t)64 * K + k0);
        *(bf16x8*)&At[srow * 40 + scol] = a0;
        *(bf16x8*)&At[(srow + 64) * 40 + scol] = a1;
        *(bf16x8*)&Bl[srow * 40 + scol] = b0;
        *(bf16x8*)&Bl[(srow + 64) * 40 + scol] = b1;
        __syncthreads();
        bf16x8 av[4], bv[4];
#pragma unroll
        for (int mt = 0; mt < 4; ++mt)
            av[mt] = *(const bf16x8*)&At[(wr * 64 + mt * 16 + ln) * 40 + kg * 8];
#pragma unroll
        for (int nt = 0; nt < 4; ++nt)
            bv[nt] = *(const bf16x8*)&Bl[(wc * 64 + nt * 16 + ln) * 40 + kg * 8];
#pragma unroll
        for (int mt = 0; mt < 4; ++mt)
#pragma unroll
            for (int nt = 0; nt < 4; ++nt)
                acc[mt][nt] = __builtin_amdgcn_mfma_f32_16x16x32_bf16(av[mt], bv[nt], acc[mt][nt], 0, 0, 0);
        __syncthreads();
    }

#pragma unroll
    for (int mt = 0; mt < 4; ++mt) {
        const int row = row0 + wr * 64 + mt * 16 + kg * 4;
#pragma unroll
        for (int nt = 0; nt < 4; ++nt) {
            const int col = col0 + wc * 64 + nt * 16 + ln;
            const f32x4 a = acc[mt][nt];
            const float bsv = bias[col];
            if constexpr (EPI == 0) {
                bf16_t* o = (bf16_t*)outp;
#pragma unroll
                for (int r = 0; r < 4; ++r)
                    o[(size_t)(row + r) * N + col] = (bf16_t)(a[r] + bsv);
            } else if constexpr (EPI == 1) {
                const float lsv = ls[col];
                float* o = (float*)outp;
#pragma unroll
                for (int r = 0; r < 4; ++r) {
                    int g = map_p_to_g(row + r);
                    size_t idx = (size_t)g * 256 + col;
                    o[idx] = xres[idx] + lsv * (a[r] + bsv);
                }
            } else if constexpr (EPI == 2) {
                bf16_t* o = (bf16_t*)outp;
#pragma unroll
                for (int r = 0; r < 4; ++r) {
                    float u = a[r] + bsv;
                    float gl = 0.5f * u * (1.f + erff(u * 0.70710678118654752f));
                    o[(size_t)(row + r) * N + col] = (bf16_t)gl;
                }
            } else {
                const float lsv = ls[col];
                float* o = (float*)outp;
#pragma unroll
                for (int r = 0; r < 4; ++r) {
                    size_t idx = (size_t)(row + r) * 256 + col;
                    o[idx] += lsv * (a[r] + bsv);
                }
            }
        }
    }
}

// ---------------- fused per-window attention ----------------
// One block per window (1024 blocks), wave `wid` handles heads wid and wid+4.
// Q/K/V fragments come straight from global qkv (each element used once -> no LDS staging);
// only P (softmax probs) goes through LDS for the D-layout -> A-layout transpose.
__global__ __launch_bounds__(256) void attn_k(const bf16_t* __restrict__ qkv,
                                              bf16_t* __restrict__ out)
{
    __shared__ bf16_t Plds[4 * 7040];     // per wave: P[80][88] (176B stride, 16B aligned, 2-way banks)
    const int t = threadIdx.x, wid = t >> 6, lane = t & 63;
    const int ln = lane & 15, kg = lane >> 4;
    bf16_t* P = &Plds[wid * 7040];
    const int w = blockIdx.x;
    const bf16_t* base = qkv + (size_t)w * 80 * 768;
    const float SCALE = 0.17677669529663689f;   // 32^-0.5

    for (int hh = 0; hh < 2; ++hh) {
        const int h = wid + hh * 4;
        const bf16_t* hb = base + h * 96;
        // S = Q K^T  (DH=32 = one MFMA K-step); A-frag rows = q tokens, B-frag rows = k tokens
        bf16x8 qa[5], kb[5];
#pragma unroll
        for (int mt = 0; mt < 5; ++mt)
            qa[mt] = *(const bf16x8*)(hb + (size_t)(mt * 16 + ln) * 768 + kg * 8);
#pragma unroll
        for (int nt = 0; nt < 5; ++nt)
            kb[nt] = *(const bf16x8*)(hb + (size_t)(nt * 16 + ln) * 768 + 32 + kg * 8);
        f32x4 S[5][5];
#pragma unroll
        for (int mt = 0; mt < 5; ++mt)
#pragma unroll
            for (int nt = 0; nt < 5; ++nt) {
                f32x4 z = {0.f, 0.f, 0.f, 0.f};
                S[mt][nt] = __builtin_amdgcn_mfma_f32_16x16x32_bf16(qa[mt], kb[nt], z, 0, 0, 0);
            }
        // softmax over rows; row n = mt*16+kg*4+r lives in 16 lanes (ln) x 5 regs (nt)
#pragma unroll
        for (int mt = 0; mt < 5; ++mt) {
#pragma unroll
            for (int r = 0; r < 4; ++r) {
                float mx = S[mt][0][r];
#pragma unroll
                for (int nt = 1; nt < 5; ++nt) mx = fmaxf(mx, S[mt][nt][r]);
                mx = fmaxf(mx, __shfl_xor(mx, 1, 64));
                mx = fmaxf(mx, __shfl_xor(mx, 2, 64));
                mx = fmaxf(mx, __shfl_xor(mx, 4, 64));
                mx = fmaxf(mx, __shfl_xor(mx, 8, 64));
                float sum = 0.f;
#pragma unroll
                for (int nt = 0; nt < 5; ++nt) {
                    float e = __expf((S[mt][nt][r] - mx) * SCALE);
                    S[mt][nt][r] = e;
                    sum += e;
                }
                sum += __shfl_xor(sum, 1, 64);
                sum += __shfl_xor(sum, 2, 64);
                sum += __shfl_xor(sum, 4, 64);
                sum += __shfl_xor(sum, 8, 64);
                float inv = 1.f / sum;
#pragma unroll
                for (int nt = 0; nt < 5; ++nt) S[mt][nt][r] *= inv;
            }
        }
        // P -> LDS (D-layout scatter), then consume as A-operand
#pragma unroll
        for (int mt = 0; mt < 5; ++mt)
#pragma unroll
            for (int nt = 0; nt < 5; ++nt)
#pragma unroll
                for (int r = 0; r < 4; ++r)
                    P[(mt * 16 + kg * 4 + r) * 88 + nt * 16 + ln] = (bf16_t)S[mt][nt][r];
        // O = P V ; K-dim = 80 tokens = 2.5 MFMA steps; dead lanes zeroed on V side
        f32x4 O[5][2];
#pragma unroll
        for (int mt = 0; mt < 5; ++mt) {
            O[mt][0] = (f32x4){0.f, 0.f, 0.f, 0.f};
            O[mt][1] = (f32x4){0.f, 0.f, 0.f, 0.f};
        }
#pragma unroll
        for (int nt2 = 0; nt2 < 2; ++nt2) {
#pragma unroll
            for (int kt = 0; kt < 3; ++kt) {
                const bool dead = (kt == 2) && (kg >= 2);
                bf16x8 bv;
#pragma unroll
                for (int j = 0; j < 8; ++j) {
                    int tok = kt * 32 + kg * 8 + j;
                    if (tok > 79) tok = 79;                       // clamp: keep loads in-bounds
                    bv[j] = hb[(size_t)tok * 768 + 64 + nt2 * 16 + ln];
                }
                if (dead) {
#pragma unroll
                    for (int j = 0; j < 8; ++j) bv[j] = (bf16_t)0.f;
                }
                int cb = kt * 32 + kg * 8;
                if (cb >= 80) cb = 0;                             // clamp: finite a * zero b = 0
#pragma unroll
                for (int mt = 0; mt < 5; ++mt) {
                    bf16x8 av = *(const bf16x8*)(P + (mt * 16 + ln) * 88 + cb);
                    O[mt][nt2] = __builtin_amdgcn_mfma_f32_16x16x32_bf16(av, bv, O[mt][nt2], 0, 0, 0);
                }
            }
        }
#pragma unroll
        for (int mt = 0; mt < 5; ++mt)
#pragma unroll
            for (int nt2 = 0; nt2 < 2; ++nt2)
#pragma unroll
                for (int r = 0; r < 4; ++r) {
                    int n = mt * 16 + kg * 4 + r;
                    out[((size_t)w * 80 + n) * 256 + h * 32 + nt2 * 16 + ln] = (bf16_t)O[mt][nt2][r];
                }
    }
}

// ---------------- launch ----------------
extern "C" void kernel_launch(void* const* d_in, const int* in_sizes, int n_in,
                              void* d_out, int out_size, void* d_ws, size_t ws_size,
                              hipStream_t stream)
{
    (void)in_sizes; (void)n_in; (void)out_size; (void)ws_size;
    const float* x     = (const float*)d_in[0];
    const float* n1g   = (const float*)d_in[1];
    const float* n1b   = (const float*)d_in[2];
    const float* qkvw  = (const float*)d_in[3];
    const float* qkvb  = (const float*)d_in[4];
    const float* projw = (const float*)d_in[5];
    const float* projb = (const float*)d_in[6];
    const float* ls1   = (const float*)d_in[7];
    const float* n2g   = (const float*)d_in[8];
    const float* n2b   = (const float*)d_in[9];
    const float* fc1w  = (const float*)d_in[10];
    const float* fc1b  = (const float*)d_in[11];
    const float* fc2w  = (const float*)d_in[12];
    const float* fc2b  = (const float*)d_in[13];
    const float* ls2   = (const float*)d_in[14];
    float* out = (float*)d_out;

    // workspace layout (bytes); h1 overlays [0,160MB) after attn+proj consume it
    char* ws = (char*)d_ws;
    bf16_t* ln1p   = (bf16_t*)(ws);                 // 81920*256 bf16 (also attn-out, also h1 head)
    bf16_t* qkv    = (bf16_t*)(ws + 41943040ull);   // 81920*768 bf16
    bf16_t* ln2    = (bf16_t*)(ws + 167772160ull);  // 81920*256 bf16
    bf16_t* wbuf   = (bf16_t*)(ws + 209715200ull);  // weights, ~1.5MB
    bf16_t* qkvwt  = wbuf;                          // [768][256]
    bf16_t* projwt = qkvwt + 768 * 256;             // [256][256]
    bf16_t* fc1wt  = projwt + 256 * 256;            // [1024][256]
    bf16_t* fc2wt  = fc1wt + 1024 * 256;            // [256][1024]
    bf16_t* attno  = ln1p;                          // overlay (ln1p dead after qkv gemm)
    bf16_t* h1     = (bf16_t*)(ws);                 // overlay (attno+qkv dead after proj)

    wconv_k<<<768,  256, 0, stream>>>(qkvw,  qkvwt, 768, 256);
    wconv_k<<<256,  256, 0, stream>>>(projw, projwt, 256, 256);
    wconv_k<<<1024, 256, 0, stream>>>(fc1w,  fc1wt, 1024, 256);
    wconv_k<<<1024, 256, 0, stream>>>(fc2w,  fc2wt, 256, 1024);

    ln_k<1><<<20480, 256, 0, stream>>>(x, n1g, n1b, ln1p);
    gemm_k<0><<<dim3(6, 640), 256, 0, stream>>>(ln1p, qkvwt, qkvb, nullptr, nullptr, qkv, 768, 256);
    attn_k<<<1024, 256, 0, stream>>>(qkv, attno);
    gemm_k<1><<<dim3(2, 640), 256, 0, stream>>>(attno, projwt, projb, x, ls1, out, 256, 256);
    ln_k<0><<<20480, 256, 0, stream>>>(out, n2g, n2b, ln2);
    gemm_k<2><<<dim3(8, 640), 256, 0, stream>>>(ln2, fc1wt, fc1b, nullptr, nullptr, h1, 1024, 256);
    gemm_k<3><<<dim3(2, 640), 256, 0, stream>>>(h1, fc2wt, fc2b, nullptr, ls2, out, 256, 1024);
}

// Round 2
// 495.590 us; speedup vs baseline: 1.0193x; 1.0193x over previous
//
#include <hip/hip_runtime.h>
#include <hip/hip_bf16.h>
#include <stdint.h>
#include <math.h>

typedef __bf16 bf16_t;
typedef __bf16 bf16x8 __attribute__((ext_vector_type(8)));
typedef __bf16 bf16x4 __attribute__((ext_vector_type(4)));
typedef float  f32x4  __attribute__((ext_vector_type(4)));

typedef __attribute__((address_space(1))) const void global_cv;
typedef __attribute__((address_space(3))) void lds_v;

// Problem constants: B=16,H=64,W=80,C=256; GH=8,GW=10; heads=8,DH=32; INNER=1024
// partition: window w=(b*8+h2)*8+w2 (h2=h%8,w2=w%8), token n=gh*10+gw (gh=h/8,gw=w/8)

__device__ __forceinline__ int map_p_to_g(int p) {
    // partition row -> original row
    int w = p / 80, n = p - w * 80;
    int b  = w >> 6, h2 = (w >> 3) & 7, w2 = w & 7;
    int gh = n / 10, gw = n - gh * 10;
    return b * 5120 + (gh * 8 + h2) * 80 + (gw * 8 + w2);
}

// LDS XOR swizzle for 128B rows: bits 4-6 ^= bits 7-9 (involution; keeps 16B alignment)
__device__ __forceinline__ int swz128(int b) { return b ^ (((b >> 7) & 7) << 4); }

// ---------------- weight convert+transpose: fp32 [K][N] -> bf16 [N][K] ----------------
__global__ __launch_bounds__(256) void wconv_k(const float* __restrict__ in,
                                               bf16_t* __restrict__ out, int N, int K)
{
    int i = blockIdx.x * 256 + threadIdx.x;   // grid sized exactly N*K/256
    int n = i / K, k = i - n * K;
    out[i] = (bf16_t)in[(size_t)k * N + n];
}

// ---------------- LayerNorm (one wave per row), optional partition permute ----------------
template <int PERM>
__global__ __launch_bounds__(256) void ln_k(const float* __restrict__ in,
                                            const float* __restrict__ gg,
                                            const float* __restrict__ bb,
                                            bf16_t* __restrict__ o)
{
    int row  = blockIdx.x * 4 + (threadIdx.x >> 6);
    int lane = threadIdx.x & 63;
    const float4 xv = *(const float4*)(in + (size_t)row * 256 + lane * 4);
    float s = xv.x + xv.y + xv.z + xv.w;
#pragma unroll
    for (int m = 1; m < 64; m <<= 1) s += __shfl_xor(s, m, 64);
    float mean = s * (1.f / 256.f);
    float d0 = xv.x - mean, d1 = xv.y - mean, d2 = xv.z - mean, d3 = xv.w - mean;
    float v = d0 * d0 + d1 * d1 + d2 * d2 + d3 * d3;
#pragma unroll
    for (int m = 1; m < 64; m <<= 1) v += __shfl_xor(v, m, 64);
    float rstd = rsqrtf(v * (1.f / 256.f) + 1e-5f);
    const float4 gv = *(const float4*)(gg + lane * 4);
    const float4 bv = *(const float4*)(bb + lane * 4);
    int orow = row;
    if (PERM) {
        int b = row / 5120, r1 = row - b * 5120;
        int h = r1 / 80, wv = r1 - h * 80;
        int gh = h >> 3, h2 = h & 7, gw = wv >> 3, w2 = wv & 7;
        orow = ((b * 8 + h2) * 8 + w2) * 80 + gh * 10 + gw;
    }
    bf16x4 ov;
    ov[0] = (bf16_t)(d0 * rstd * gv.x + bv.x);
    ov[1] = (bf16_t)(d1 * rstd * gv.y + bv.y);
    ov[2] = (bf16_t)(d2 * rstd * gv.z + bv.z);
    ov[3] = (bf16_t)(d3 * rstd * gv.w + bv.w);
    *(bf16x4*)(o + (size_t)orow * 256 + lane * 4) = ov;
}

// ---------------- tiled bf16 MFMA GEMM (m97 structure): C[81920,N] = A * Bt^T ----------------
// 128x128 tile, BK=64, 4 waves (2x2), each wave 64x64 (4x4 frags of 16x16x32).
// Staging: global_load_lds width-16 into linear LDS with both-sides XOR swizzle (rule 21):
//   content at physical byte b is global data for semantic byte swz128(b); reads use swz128.
// EPI: 0 = bf16 out (+bias)   [qkv]
//      1 = fp32 out = x[g] + ls*(acc+bias), grid-reverse row map  [proj]
//      2 = bf16 out = gelu(acc+bias)  [fc1]
//      3 = fp32 out[idx] += ls*(acc+bias)  [fc2, in-place on d_out]
template <int EPI>
__global__ __launch_bounds__(256) void gemm_k(const bf16_t* __restrict__ A,
                                              const bf16_t* __restrict__ Bt,
                                              const float* __restrict__ bias,
                                              const float* __restrict__ xres,
                                              const float* __restrict__ ls,
                                              void* __restrict__ outp,
                                              int N, int K)
{
    __shared__ bf16_t At[128 * 64];   // 16 KB, linear [row][64] (128 B rows), swizzled content
    __shared__ bf16_t Bl[128 * 64];
    const int t = threadIdx.x;
    const int wid = t >> 6, lane = t & 63;
    const int wr = wid >> 1, wc = wid & 1;
    const int ln = lane & 15, kg = lane >> 4;
    const int row0 = blockIdx.y * 128;
    const int col0 = blockIdx.x * 128;

    const f32x4 fz = {0.f, 0.f, 0.f, 0.f};
    f32x4 acc[4][4];
#pragma unroll
    for (int i = 0; i < 4; ++i)
#pragma unroll
        for (int j = 0; j < 4; ++j) acc[i][j] = fz;

    // staging map: issue i, this thread fills LDS chunk c=(i*4+wid)*64+lane (16 B).
    // source semantic byte = swz128(c*16) -> row, col within the [128][128B] tile.
    int srow[4], scolb[4];
#pragma unroll
    for (int i = 0; i < 4; ++i) {
        int beta  = ((i * 4 + wid) * 64 + lane) * 16;
        int gamma = swz128(beta);
        srow[i]  = gamma >> 7;
        scolb[i] = gamma & 127;
    }

    const char* Ab = (const char*)(A  + (size_t)row0 * K);
    const char* Bb = (const char*)(Bt + (size_t)col0 * K);
    char* AtB = (char*)At;
    char* BlB = (char*)Bl;

    for (int k0 = 0; k0 < K; k0 += 64) {
        const size_t kbyte = (size_t)k0 * 2;
#pragma unroll
        for (int i = 0; i < 4; ++i)
            __builtin_amdgcn_global_load_lds(
                (global_cv*)(Ab + (size_t)srow[i] * (K * 2) + kbyte + scolb[i]),
                (lds_v*)(AtB + (i * 4 + wid) * 1024), 16, 0, 0);
#pragma unroll
        for (int i = 0; i < 4; ++i)
            __builtin_amdgcn_global_load_lds(
                (global_cv*)(Bb + (size_t)srow[i] * (K * 2) + kbyte + scolb[i]),
                (lds_v*)(BlB + (i * 4 + wid) * 1024), 16, 0, 0);
        __syncthreads();   // compiler drains vmcnt(0) before s_barrier
#pragma unroll
        for (int kk = 0; kk < 2; ++kk) {
            bf16x8 av[4], bv[4];
#pragma unroll
            for (int mt = 0; mt < 4; ++mt) {
                int row = wr * 64 + mt * 16 + ln;
                av[mt] = *(const bf16x8*)(AtB + swz128(row * 128 + kk * 64 + kg * 16));
            }
#pragma unroll
            for (int nt = 0; nt < 4; ++nt) {
                int row = wc * 64 + nt * 16 + ln;
                bv[nt] = *(const bf16x8*)(BlB + swz128(row * 128 + kk * 64 + kg * 16));
            }
#pragma unroll
            for (int mt = 0; mt < 4; ++mt)
#pragma unroll
                for (int nt = 0; nt < 4; ++nt)
                    acc[mt][nt] = __builtin_amdgcn_mfma_f32_16x16x32_bf16(av[mt], bv[nt], acc[mt][nt], 0, 0, 0);
        }
        __syncthreads();   // protect LDS before next staging round
    }

#pragma unroll
    for (int mt = 0; mt < 4; ++mt) {
        const int row = row0 + wr * 64 + mt * 16 + kg * 4;
#pragma unroll
        for (int nt = 0; nt < 4; ++nt) {
            const int col = col0 + wc * 64 + nt * 16 + ln;
            const f32x4 a = acc[mt][nt];
            const float bsv = bias[col];
            if constexpr (EPI == 0) {
                bf16_t* o = (bf16_t*)outp;
#pragma unroll
                for (int r = 0; r < 4; ++r)
                    o[(size_t)(row + r) * N + col] = (bf16_t)(a[r] + bsv);
            } else if constexpr (EPI == 1) {
                const float lsv = ls[col];
                float* o = (float*)outp;
#pragma unroll
                for (int r = 0; r < 4; ++r) {
                    int g = map_p_to_g(row + r);
                    size_t idx = (size_t)g * 256 + col;
                    o[idx] = xres[idx] + lsv * (a[r] + bsv);
                }
            } else if constexpr (EPI == 2) {
                bf16_t* o = (bf16_t*)outp;
#pragma unroll
                for (int r = 0; r < 4; ++r) {
                    float u = a[r] + bsv;
                    float gl = 0.5f * u * (1.f + erff(u * 0.70710678118654752f));
                    o[(size_t)(row + r) * N + col] = (bf16_t)gl;
                }
            } else {
                const float lsv = ls[col];
                float* o = (float*)outp;
#pragma unroll
                for (int r = 0; r < 4; ++r) {
                    size_t idx = (size_t)(row + r) * 256 + col;
                    o[idx] += lsv * (a[r] + bsv);
                }
            }
        }
    }
}

// ---------------- fused per-window attention ----------------
// One block per window (1024 blocks), wave `wid` handles heads wid and wid+4.
// Q/K/V fragments come straight from global qkv (each element used once -> no LDS staging);
// only P (softmax probs) goes through LDS for the D-layout -> A-layout transpose.
__global__ __launch_bounds__(256) void attn_k(const bf16_t* __restrict__ qkv,
                                              bf16_t* __restrict__ out)
{
    __shared__ bf16_t Plds[4 * 7040];     // per wave: P[80][88] (176B stride, 16B aligned, 2-way banks)
    const int t = threadIdx.x, wid = t >> 6, lane = t & 63;
    const int ln = lane & 15, kg = lane >> 4;
    bf16_t* P = &Plds[wid * 7040];
    const int w = blockIdx.x;
    const bf16_t* base = qkv + (size_t)w * 80 * 768;
    const float SCALE = 0.17677669529663689f;   // 32^-0.5

    for (int hh = 0; hh < 2; ++hh) {
        const int h = wid + hh * 4;
        const bf16_t* hb = base + h * 96;
        // S = Q K^T  (DH=32 = one MFMA K-step); A-frag rows = q tokens, B-frag rows = k tokens
        bf16x8 qa[5], kb[5];
#pragma unroll
        for (int mt = 0; mt < 5; ++mt)
            qa[mt] = *(const bf16x8*)(hb + (size_t)(mt * 16 + ln) * 768 + kg * 8);
#pragma unroll
        for (int nt = 0; nt < 5; ++nt)
            kb[nt] = *(const bf16x8*)(hb + (size_t)(nt * 16 + ln) * 768 + 32 + kg * 8);
        f32x4 S[5][5];
#pragma unroll
        for (int mt = 0; mt < 5; ++mt)
#pragma unroll
            for (int nt = 0; nt < 5; ++nt) {
                f32x4 z = {0.f, 0.f, 0.f, 0.f};
                S[mt][nt] = __builtin_amdgcn_mfma_f32_16x16x32_bf16(qa[mt], kb[nt], z, 0, 0, 0);
            }
        // softmax over rows; row n = mt*16+kg*4+r lives in 16 lanes (ln) x 5 regs (nt)
#pragma unroll
        for (int mt = 0; mt < 5; ++mt) {
#pragma unroll
            for (int r = 0; r < 4; ++r) {
                float mx = S[mt][0][r];
#pragma unroll
                for (int nt = 1; nt < 5; ++nt) mx = fmaxf(mx, S[mt][nt][r]);
                mx = fmaxf(mx, __shfl_xor(mx, 1, 64));
                mx = fmaxf(mx, __shfl_xor(mx, 2, 64));
                mx = fmaxf(mx, __shfl_xor(mx, 4, 64));
                mx = fmaxf(mx, __shfl_xor(mx, 8, 64));
                float sum = 0.f;
#pragma unroll
                for (int nt = 0; nt < 5; ++nt) {
                    float e = __expf((S[mt][nt][r] - mx) * SCALE);
                    S[mt][nt][r] = e;
                    sum += e;
                }
                sum += __shfl_xor(sum, 1, 64);
                sum += __shfl_xor(sum, 2, 64);
                sum += __shfl_xor(sum, 4, 64);
                sum += __shfl_xor(sum, 8, 64);
                float inv = 1.f / sum;
#pragma unroll
                for (int nt = 0; nt < 5; ++nt) S[mt][nt][r] *= inv;
            }
        }
        // P -> LDS (D-layout scatter), then consume as A-operand
#pragma unroll
        for (int mt = 0; mt < 5; ++mt)
#pragma unroll
            for (int nt = 0; nt < 5; ++nt)
#pragma unroll
                for (int r = 0; r < 4; ++r)
                    P[(mt * 16 + kg * 4 + r) * 88 + nt * 16 + ln] = (bf16_t)S[mt][nt][r];
        // O = P V ; K-dim = 80 tokens = 2.5 MFMA steps; dead lanes zeroed on V side
        f32x4 O[5][2];
#pragma unroll
        for (int mt = 0; mt < 5; ++mt) {
            O[mt][0] = (f32x4){0.f, 0.f, 0.f, 0.f};
            O[mt][1] = (f32x4){0.f, 0.f, 0.f, 0.f};
        }
#pragma unroll
        for (int nt2 = 0; nt2 < 2; ++nt2) {
#pragma unroll
            for (int kt = 0; kt < 3; ++kt) {
                const bool dead = (kt == 2) && (kg >= 2);
                bf16x8 bv;
#pragma unroll
                for (int j = 0; j < 8; ++j) {
                    int tok = kt * 32 + kg * 8 + j;
                    if (tok > 79) tok = 79;                       // clamp: keep loads in-bounds
                    bv[j] = hb[(size_t)tok * 768 + 64 + nt2 * 16 + ln];
                }
                if (dead) {
#pragma unroll
                    for (int j = 0; j < 8; ++j) bv[j] = (bf16_t)0.f;
                }
                int cb = kt * 32 + kg * 8;
                if (cb >= 80) cb = 0;                             // clamp: finite a * zero b = 0
#pragma unroll
                for (int mt = 0; mt < 5; ++mt) {
                    bf16x8 av = *(const bf16x8*)(P + (mt * 16 + ln) * 88 + cb);
                    O[mt][nt2] = __builtin_amdgcn_mfma_f32_16x16x32_bf16(av, bv, O[mt][nt2], 0, 0, 0);
                }
            }
        }
#pragma unroll
        for (int mt = 0; mt < 5; ++mt)
#pragma unroll
            for (int nt2 = 0; nt2 < 2; ++nt2)
#pragma unroll
                for (int r = 0; r < 4; ++r) {
                    int n = mt * 16 + kg * 4 + r;
                    out[((size_t)w * 80 + n) * 256 + h * 32 + nt2 * 16 + ln] = (bf16_t)O[mt][nt2][r];
                }
    }
}

// ---------------- launch ----------------
extern "C" void kernel_launch(void* const* d_in, const int* in_sizes, int n_in,
                              void* d_out, int out_size, void* d_ws, size_t ws_size,
                              hipStream_t stream)
{
    (void)in_sizes; (void)n_in; (void)out_size; (void)ws_size;
    const float* x     = (const float*)d_in[0];
    const float* n1g   = (const float*)d_in[1];
    const float* n1b   = (const float*)d_in[2];
    const float* qkvw  = (const float*)d_in[3];
    const float* qkvb  = (const float*)d_in[4];
    const float* projw = (const float*)d_in[5];
    const float* projb = (const float*)d_in[6];
    const float* ls1   = (const float*)d_in[7];
    const float* n2g   = (const float*)d_in[8];
    const float* n2b   = (const float*)d_in[9];
    const float* fc1w  = (const float*)d_in[10];
    const float* fc1b  = (const float*)d_in[11];
    const float* fc2w  = (const float*)d_in[12];
    const float* fc2b  = (const float*)d_in[13];
    const float* ls2   = (const float*)d_in[14];
    float* out = (float*)d_out;

    // workspace layout (bytes); h1 overlays [0,160MB) after attn+proj consume it
    char* ws = (char*)d_ws;
    bf16_t* ln1p   = (bf16_t*)(ws);                 // 81920*256 bf16 (also attn-out, also h1 head)
    bf16_t* qkv    = (bf16_t*)(ws + 41943040ull);   // 81920*768 bf16
    bf16_t* ln2    = (bf16_t*)(ws + 167772160ull);  // 81920*256 bf16
    bf16_t* wbuf   = (bf16_t*)(ws + 209715200ull);  // weights, ~1.5MB
    bf16_t* qkvwt  = wbuf;                          // [768][256]
    bf16_t* projwt = qkvwt + 768 * 256;             // [256][256]
    bf16_t* fc1wt  = projwt + 256 * 256;            // [1024][256]
    bf16_t* fc2wt  = fc1wt + 1024 * 256;            // [256][1024]
    bf16_t* attno  = ln1p;                          // overlay (ln1p dead after qkv gemm)
    bf16_t* h1     = (bf16_t*)(ws);                 // overlay (attno+qkv dead after proj)

    wconv_k<<<768,  256, 0, stream>>>(qkvw,  qkvwt, 768, 256);
    wconv_k<<<256,  256, 0, stream>>>(projw, projwt, 256, 256);
    wconv_k<<<1024, 256, 0, stream>>>(fc1w,  fc1wt, 1024, 256);
    wconv_k<<<1024, 256, 0, stream>>>(fc2w,  fc2wt, 256, 1024);

    ln_k<1><<<20480, 256, 0, stream>>>(x, n1g, n1b, ln1p);
    gemm_k<0><<<dim3(6, 640), 256, 0, stream>>>(ln1p, qkvwt, qkvb, nullptr, nullptr, qkv, 768, 256);
    attn_k<<<1024, 256, 0, stream>>>(qkv, attno);
    gemm_k<1><<<dim3(2, 640), 256, 0, stream>>>(attno, projwt, projb, x, ls1, out, 256, 256);
    ln_k<0><<<20480, 256, 0, stream>>>(out, n2g, n2b, ln2);
    gemm_k<2><<<dim3(8, 640), 256, 0, stream>>>(ln2, fc1wt, fc1b, nullptr, nullptr, h1, 1024, 256);
    gemm_k<3><<<dim3(2, 640), 256, 0, stream>>>(h1, fc2wt, fc2b, nullptr, ls2, out, 256, 1024);
}

// Round 3
// 491.458 us; speedup vs baseline: 1.0279x; 1.0084x over previous
//
#include <hip/hip_runtime.h>
#include <hip/hip_bf16.h>
#include <stdint.h>
#include <math.h>

typedef __bf16 bf16_t;
typedef __bf16 bf16x8 __attribute__((ext_vector_type(8)));
typedef __bf16 bf16x4 __attribute__((ext_vector_type(4)));
typedef float  f32x4  __attribute__((ext_vector_type(4)));

typedef __attribute__((address_space(1))) const void global_cv;
typedef __attribute__((address_space(3))) void lds_v;

// Problem constants: B=16,H=64,W=80,C=256; GH=8,GW=10; heads=8,DH=32; INNER=1024

__device__ __forceinline__ int map_p_to_g(int p) {
    int w = p / 80, n = p - w * 80;
    int b  = w >> 6, h2 = (w >> 3) & 7, w2 = w & 7;
    int gh = n / 10, gw = n - gh * 10;
    return b * 5120 + (gh * 8 + h2) * 80 + (gw * 8 + w2);
}

// XOR swizzle for 128-B LDS rows: bits 4-6 ^= bits 7-9 (involution, keeps 16B align)
__device__ __forceinline__ int swz128(int b) { return b ^ (((b >> 7) & 7) << 4); }

// ---------------- weight convert+transpose: fp32 [K][N] -> bf16 [N][K] ----------------
__global__ __launch_bounds__(256) void wconv_k(const float* __restrict__ in,
                                               bf16_t* __restrict__ out, int N, int K)
{
    int i = blockIdx.x * 256 + threadIdx.x;
    int n = i / K, k = i - n * K;
    out[i] = (bf16_t)in[(size_t)k * N + n];
}

// ---------------- LayerNorm (one wave per row), optional partition permute ----------------
template <int PERM>
__global__ __launch_bounds__(256) void ln_k(const float* __restrict__ in,
                                            const float* __restrict__ gg,
                                            const float* __restrict__ bb,
                                            bf16_t* __restrict__ o)
{
    int row  = blockIdx.x * 4 + (threadIdx.x >> 6);
    int lane = threadIdx.x & 63;
    const float4 xv = *(const float4*)(in + (size_t)row * 256 + lane * 4);
    float s = xv.x + xv.y + xv.z + xv.w;
#pragma unroll
    for (int m = 1; m < 64; m <<= 1) s += __shfl_xor(s, m, 64);
    float mean = s * (1.f / 256.f);
    float d0 = xv.x - mean, d1 = xv.y - mean, d2 = xv.z - mean, d3 = xv.w - mean;
    float v = d0 * d0 + d1 * d1 + d2 * d2 + d3 * d3;
#pragma unroll
    for (int m = 1; m < 64; m <<= 1) v += __shfl_xor(v, m, 64);
    float rstd = rsqrtf(v * (1.f / 256.f) + 1e-5f);
    const float4 gv = *(const float4*)(gg + lane * 4);
    const float4 bv = *(const float4*)(bb + lane * 4);
    int orow = row;
    if (PERM) {
        int b = row / 5120, r1 = row - b * 5120;
        int h = r1 / 80, wv = r1 - h * 80;
        int gh = h >> 3, h2 = h & 7, gw = wv >> 3, w2 = wv & 7;
        orow = ((b * 8 + h2) * 8 + w2) * 80 + gh * 10 + gw;
    }
    bf16x4 ov;
    ov[0] = (bf16_t)(d0 * rstd * gv.x + bv.x);
    ov[1] = (bf16_t)(d1 * rstd * gv.y + bv.y);
    ov[2] = (bf16_t)(d2 * rstd * gv.z + bv.z);
    ov[3] = (bf16_t)(d3 * rstd * gv.w + bv.w);
    *(bf16x4*)(o + (size_t)orow * 256 + lane * 4) = ov;
}

// ---------------- tiled bf16 MFMA GEMM body (m97 structure) ----------------
// 128x128 tile, BK=64, 4 waves (2x2). Both-sides swz128 (rule 21).
// EPI 0 = bf16 out (+bias) [qkv]; EPI 1 = fp32 out = x[g]+ls*(acc+bias), grid-reverse [proj]
template <int EPI>
__device__ __forceinline__ void gemm_body(const bf16_t* __restrict__ A,
                                          const bf16_t* __restrict__ Bt,
                                          const float* __restrict__ bias,
                                          const float* __restrict__ xres,
                                          const float* __restrict__ ls,
                                          void* __restrict__ outp,
                                          int N, int K)
{
    __shared__ bf16_t At[128 * 64];
    __shared__ bf16_t Bl[128 * 64];
    const int t = threadIdx.x;
    const int wid = t >> 6, lane = t & 63;
    const int wr = wid >> 1, wc = wid & 1;
    const int ln = lane & 15, kg = lane >> 4;
    const int row0 = blockIdx.y * 128;
    const int col0 = blockIdx.x * 128;

    const f32x4 fz = {0.f, 0.f, 0.f, 0.f};
    f32x4 acc[4][4];
#pragma unroll
    for (int i = 0; i < 4; ++i)
#pragma unroll
        for (int j = 0; j < 4; ++j) acc[i][j] = fz;

    int srow[4], scolb[4];
#pragma unroll
    for (int i = 0; i < 4; ++i) {
        int beta  = ((i * 4 + wid) * 64 + lane) * 16;
        int gamma = swz128(beta);
        srow[i]  = gamma >> 7;
        scolb[i] = gamma & 127;
    }

    const char* Ab = (const char*)(A  + (size_t)row0 * K);
    const char* Bb = (const char*)(Bt + (size_t)col0 * K);
    char* AtB = (char*)At;
    char* BlB = (char*)Bl;

    for (int k0 = 0; k0 < K; k0 += 64) {
        const size_t kbyte = (size_t)k0 * 2;
#pragma unroll
        for (int i = 0; i < 4; ++i)
            __builtin_amdgcn_global_load_lds(
                (global_cv*)(Ab + (size_t)srow[i] * (K * 2) + kbyte + scolb[i]),
                (lds_v*)(AtB + (i * 4 + wid) * 1024), 16, 0, 0);
#pragma unroll
        for (int i = 0; i < 4; ++i)
            __builtin_amdgcn_global_load_lds(
                (global_cv*)(Bb + (size_t)srow[i] * (K * 2) + kbyte + scolb[i]),
                (lds_v*)(BlB + (i * 4 + wid) * 1024), 16, 0, 0);
        __syncthreads();
#pragma unroll
        for (int kk = 0; kk < 2; ++kk) {
            bf16x8 av[4], bv[4];
#pragma unroll
            for (int mt = 0; mt < 4; ++mt) {
                int row = wr * 64 + mt * 16 + ln;
                av[mt] = *(const bf16x8*)(AtB + swz128(row * 128 + kk * 64 + kg * 16));
            }
#pragma unroll
            for (int nt = 0; nt < 4; ++nt) {
                int row = wc * 64 + nt * 16 + ln;
                bv[nt] = *(const bf16x8*)(BlB + swz128(row * 128 + kk * 64 + kg * 16));
            }
#pragma unroll
            for (int mt = 0; mt < 4; ++mt)
#pragma unroll
                for (int nt = 0; nt < 4; ++nt)
                    acc[mt][nt] = __builtin_amdgcn_mfma_f32_16x16x32_bf16(av[mt], bv[nt], acc[mt][nt], 0, 0, 0);
        }
        __syncthreads();
    }

#pragma unroll
    for (int mt = 0; mt < 4; ++mt) {
        const int row = row0 + wr * 64 + mt * 16 + kg * 4;
#pragma unroll
        for (int nt = 0; nt < 4; ++nt) {
            const int col = col0 + wc * 64 + nt * 16 + ln;
            const f32x4 a = acc[mt][nt];
            const float bsv = bias[col];
            if constexpr (EPI == 0) {
                bf16_t* o = (bf16_t*)outp;
#pragma unroll
                for (int r = 0; r < 4; ++r)
                    o[(size_t)(row + r) * N + col] = (bf16_t)(a[r] + bsv);
            } else {
                const float lsv = ls[col];
                float* o = (float*)outp;
#pragma unroll
                for (int r = 0; r < 4; ++r) {
                    int g = map_p_to_g(row + r);
                    size_t idx = (size_t)g * 256 + col;
                    o[idx] = xres[idx] + lsv * (a[r] + bsv);
                }
            }
        }
    }
}

__global__ __launch_bounds__(256) void gemm_qkv_k(const bf16_t* A, const bf16_t* Bt,
                                                  const float* bias, void* outp, int N, int K)
{ gemm_body<0>(A, Bt, bias, nullptr, nullptr, outp, N, K); }

__global__ __launch_bounds__(256) void gemm_proj_k(const bf16_t* A, const bf16_t* Bt,
                                                   const float* bias, const float* xres,
                                                   const float* ls, void* outp, int N, int K)
{ gemm_body<1>(A, Bt, bias, xres, ls, outp, N, K); }

// ---------------- fused MLP: out += ls2 * (gelu(A@W1^T + b1) @ W2^T + b2) ----------------
// Block = 64 rows x full 256 out-cols; 4 waves, each owning a 64-col strip (wc).
// Per inner-chunk c (8 chunks of 128): fc1 in 4x 64-k substeps into accT ->
// exact GELU -> T in LDS -> fc2 in 4x 32-k substeps accumulating accO.
// LDS: A[64][256] (persistent, 512B rows) + T[64][128] (256B rows) + W union 16KB = 64 KB.
// All buffers XOR-swizzled per G4; staging sources inverse-swizzled (rule 21).
__global__ __launch_bounds__(256) void mlp_k(const bf16_t* __restrict__ A,    // ln2 [81920][256]
                                             const bf16_t* __restrict__ W1,   // [1024][256]
                                             const float* __restrict__ b1,    // [1024]
                                             const bf16_t* __restrict__ W2,   // [256][1024]
                                             const float* __restrict__ b2,    // [256]
                                             const float* __restrict__ ls2,   // [256]
                                             float* __restrict__ out)         // [81920][256] RMW
{
    __shared__ bf16_t Al[64 * 256];   // 32 KB
    __shared__ bf16_t Tl[64 * 128];   // 16 KB
    __shared__ bf16_t Wl[8192];       // 16 KB union (fc1 slice [128][64] / fc2 slice [256][32])
    const int t = threadIdx.x, lane = t & 63;
    const int ln = lane & 15, kg = lane >> 4;
    const int wc = t >> 6;
    const int row0 = blockIdx.x * 64;

    char* Alb = (char*)Al;
    char* Tlb = (char*)Tl;
    char* Wlb = (char*)Wl;

    // ---- stage A tile once: 32 KB contiguous global, per-row XOR (512-B rows)
    {
        const char* Ab = (const char*)(A + (size_t)row0 * 256);
#pragma unroll
        for (int i = 0; i < 8; ++i) {
            int p   = (i * 256 + t) * 16;
            int row = p >> 9;
            int sem = (p & 511) ^ ((row & 7) << 4);
            __builtin_amdgcn_global_load_lds((global_cv*)(Ab + (size_t)row * 512 + sem),
                                             (lds_v*)(Alb + p), 16, 0, 0);
        }
    }

    const f32x4 fz = {0.f, 0.f, 0.f, 0.f};
    f32x4 accO[4][4];
#pragma unroll
    for (int i = 0; i < 4; ++i)
#pragma unroll
        for (int j = 0; j < 4; ++j) accO[i][j] = fz;

    for (int c = 0; c < 8; ++c) {
        f32x4 accT[4][2];
#pragma unroll
        for (int i = 0; i < 4; ++i) { accT[i][0] = fz; accT[i][1] = fz; }

        // ---- fc1: T_chunk = A @ W1[c*128..+128]^T ; 4 substeps of 64-k
        for (int s = 0; s < 4; ++s) {
            const char* Wb = (const char*)W1 + (size_t)(c * 128) * 512 + s * 128;
#pragma unroll
            for (int i = 0; i < 4; ++i) {
                int p   = (i * 256 + t) * 16;
                int row = p >> 7;                          // slice rows are 128 B
                int sem = (p & 127) ^ ((row & 7) << 4);
                __builtin_amdgcn_global_load_lds((global_cv*)(Wb + (size_t)row * 512 + sem),
                                                 (lds_v*)(Wlb + p), 16, 0, 0);
            }
            __syncthreads();
            bf16x8 av[4][2], wv[2][2];
#pragma unroll
            for (int mt = 0; mt < 4; ++mt) {
                int arow = mt * 16 + ln;
#pragma unroll
                for (int kk = 0; kk < 2; ++kk) {
                    int sem = s * 128 + kk * 64 + kg * 16;
                    av[mt][kk] = *(const bf16x8*)(Alb + arow * 512 + (sem ^ ((arow & 7) << 4)));
                }
            }
#pragma unroll
            for (int nt = 0; nt < 2; ++nt) {
                int wrow = wc * 32 + nt * 16 + ln;
#pragma unroll
                for (int kk = 0; kk < 2; ++kk) {
                    int sem = kk * 64 + kg * 16;
                    wv[nt][kk] = *(const bf16x8*)(Wlb + wrow * 128 + (sem ^ ((wrow & 7) << 4)));
                }
            }
#pragma unroll
            for (int kk = 0; kk < 2; ++kk)
#pragma unroll
                for (int mt = 0; mt < 4; ++mt)
#pragma unroll
                    for (int nt = 0; nt < 2; ++nt)
                        accT[mt][nt] = __builtin_amdgcn_mfma_f32_16x16x32_bf16(av[mt][kk], wv[nt][kk], accT[mt][nt], 0, 0, 0);
            __syncthreads();
        }

        // ---- exact GELU + T -> LDS (256-B rows, XOR (row&7)<<4)
#pragma unroll
        for (int nt = 0; nt < 2; ++nt) {
            int tc = wc * 32 + nt * 16 + ln;
            float bs = b1[c * 128 + tc];
#pragma unroll
            for (int mt = 0; mt < 4; ++mt)
#pragma unroll
                for (int r = 0; r < 4; ++r) {
                    float u  = accT[mt][nt][r] + bs;
                    float gl = 0.5f * u * (1.f + erff(u * 0.70710678118654752f));
                    int trow = mt * 16 + kg * 4 + r;
                    int addr = trow * 256 + ((tc * 2) ^ ((trow & 7) << 4));
                    *(bf16_t*)(Tlb + addr) = (bf16_t)gl;
                }
        }
        __syncthreads();

        // ---- fc2: accO += T_chunk @ W2[:, c*128..+128]^T ; 4 substeps of 32-k
        for (int s2 = 0; s2 < 4; ++s2) {
            const char* Wb2 = (const char*)W2 + (size_t)c * 256 + s2 * 64;   // W2 rows are 2048 B
#pragma unroll
            for (int i = 0; i < 4; ++i) {
                int p   = (i * 256 + t) * 16;
                int row = p >> 6;                          // slice rows are 64 B
                int sem = (p & 63) ^ ((row & 3) << 4);
                __builtin_amdgcn_global_load_lds((global_cv*)(Wb2 + (size_t)row * 2048 + sem),
                                                 (lds_v*)(Wlb + p), 16, 0, 0);
            }
            __syncthreads();
            bf16x8 tv[4], w2v[4];
#pragma unroll
            for (int mt = 0; mt < 4; ++mt) {
                int trow = mt * 16 + ln;
                int sem  = s2 * 64 + kg * 16;
                tv[mt] = *(const bf16x8*)(Tlb + trow * 256 + (sem ^ ((trow & 7) << 4)));
            }
#pragma unroll
            for (int nt = 0; nt < 4; ++nt) {
                int wrow = wc * 64 + nt * 16 + ln;
                int sem  = kg * 16;
                w2v[nt] = *(const bf16x8*)(Wlb + wrow * 64 + (sem ^ ((wrow & 3) << 4)));
            }
#pragma unroll
            for (int mt = 0; mt < 4; ++mt)
#pragma unroll
                for (int nt = 0; nt < 4; ++nt)
                    accO[mt][nt] = __builtin_amdgcn_mfma_f32_16x16x32_bf16(tv[mt], w2v[nt], accO[mt][nt], 0, 0, 0);
            __syncthreads();
        }
    }

    // ---- epilogue: out += ls2 * (accO + b2)   (rows are plain layout)
#pragma unroll
    for (int nt = 0; nt < 4; ++nt) {
        const int col = wc * 64 + nt * 16 + ln;
        const float lsv = ls2[col], bsv = b2[col];
#pragma unroll
        for (int mt = 0; mt < 4; ++mt) {
            const int row = row0 + mt * 16 + kg * 4;
#pragma unroll
            for (int r = 0; r < 4; ++r) {
                size_t idx = (size_t)(row + r) * 256 + col;
                out[idx] += lsv * (accO[mt][nt][r] + bsv);
            }
        }
    }
}

// ---------------- fused per-window attention ----------------
__global__ __launch_bounds__(256) void attn_k(const bf16_t* __restrict__ qkv,
                                              bf16_t* __restrict__ out)
{
    __shared__ bf16_t Plds[4 * 7040];
    const int t = threadIdx.x, wid = t >> 6, lane = t & 63;
    const int ln = lane & 15, kg = lane >> 4;
    bf16_t* P = &Plds[wid * 7040];
    const int w = blockIdx.x;
    const bf16_t* base = qkv + (size_t)w * 80 * 768;
    const float SCALE = 0.17677669529663689f;

    for (int hh = 0; hh < 2; ++hh) {
        const int h = wid + hh * 4;
        const bf16_t* hb = base + h * 96;
        bf16x8 qa[5], kb[5];
#pragma unroll
        for (int mt = 0; mt < 5; ++mt)
            qa[mt] = *(const bf16x8*)(hb + (size_t)(mt * 16 + ln) * 768 + kg * 8);
#pragma unroll
        for (int nt = 0; nt < 5; ++nt)
            kb[nt] = *(const bf16x8*)(hb + (size_t)(nt * 16 + ln) * 768 + 32 + kg * 8);
        f32x4 S[5][5];
#pragma unroll
        for (int mt = 0; mt < 5; ++mt)
#pragma unroll
            for (int nt = 0; nt < 5; ++nt) {
                f32x4 z = {0.f, 0.f, 0.f, 0.f};
                S[mt][nt] = __builtin_amdgcn_mfma_f32_16x16x32_bf16(qa[mt], kb[nt], z, 0, 0, 0);
            }
#pragma unroll
        for (int mt = 0; mt < 5; ++mt) {
#pragma unroll
            for (int r = 0; r < 4; ++r) {
                float mx = S[mt][0][r];
#pragma unroll
                for (int nt = 1; nt < 5; ++nt) mx = fmaxf(mx, S[mt][nt][r]);
                mx = fmaxf(mx, __shfl_xor(mx, 1, 64));
                mx = fmaxf(mx, __shfl_xor(mx, 2, 64));
                mx = fmaxf(mx, __shfl_xor(mx, 4, 64));
                mx = fmaxf(mx, __shfl_xor(mx, 8, 64));
                float sum = 0.f;
#pragma unroll
                for (int nt = 0; nt < 5; ++nt) {
                    float e = __expf((S[mt][nt][r] - mx) * SCALE);
                    S[mt][nt][r] = e;
                    sum += e;
                }
                sum += __shfl_xor(sum, 1, 64);
                sum += __shfl_xor(sum, 2, 64);
                sum += __shfl_xor(sum, 4, 64);
                sum += __shfl_xor(sum, 8, 64);
                float inv = 1.f / sum;
#pragma unroll
                for (int nt = 0; nt < 5; ++nt) S[mt][nt][r] *= inv;
            }
        }
#pragma unroll
        for (int mt = 0; mt < 5; ++mt)
#pragma unroll
            for (int nt = 0; nt < 5; ++nt)
#pragma unroll
                for (int r = 0; r < 4; ++r)
                    P[(mt * 16 + kg * 4 + r) * 88 + nt * 16 + ln] = (bf16_t)S[mt][nt][r];
        f32x4 O[5][2];
#pragma unroll
        for (int mt = 0; mt < 5; ++mt) {
            O[mt][0] = (f32x4){0.f, 0.f, 0.f, 0.f};
            O[mt][1] = (f32x4){0.f, 0.f, 0.f, 0.f};
        }
#pragma unroll
        for (int nt2 = 0; nt2 < 2; ++nt2) {
#pragma unroll
            for (int kt = 0; kt < 3; ++kt) {
                const bool dead = (kt == 2) && (kg >= 2);
                bf16x8 bv;
#pragma unroll
                for (int j = 0; j < 8; ++j) {
                    int tok = kt * 32 + kg * 8 + j;
                    if (tok > 79) tok = 79;
                    bv[j] = hb[(size_t)tok * 768 + 64 + nt2 * 16 + ln];
                }
                if (dead) {
#pragma unroll
                    for (int j = 0; j < 8; ++j) bv[j] = (bf16_t)0.f;
                }
                int cb = kt * 32 + kg * 8;
                if (cb >= 80) cb = 0;
#pragma unroll
                for (int mt = 0; mt < 5; ++mt) {
                    bf16x8 av = *(const bf16x8*)(P + (mt * 16 + ln) * 88 + cb);
                    O[mt][nt2] = __builtin_amdgcn_mfma_f32_16x16x32_bf16(av, bv, O[mt][nt2], 0, 0, 0);
                }
            }
        }
#pragma unroll
        for (int mt = 0; mt < 5; ++mt)
#pragma unroll
            for (int nt2 = 0; nt2 < 2; ++nt2)
#pragma unroll
                for (int r = 0; r < 4; ++r) {
                    int n = mt * 16 + kg * 4 + r;
                    out[((size_t)w * 80 + n) * 256 + h * 32 + nt2 * 16 + ln] = (bf16_t)O[mt][nt2][r];
                }
    }
}

// ---------------- launch ----------------
extern "C" void kernel_launch(void* const* d_in, const int* in_sizes, int n_in,
                              void* d_out, int out_size, void* d_ws, size_t ws_size,
                              hipStream_t stream)
{
    (void)in_sizes; (void)n_in; (void)out_size; (void)ws_size;
    const float* x     = (const float*)d_in[0];
    const float* n1g   = (const float*)d_in[1];
    const float* n1b   = (const float*)d_in[2];
    const float* qkvw  = (const float*)d_in[3];
    const float* qkvb  = (const float*)d_in[4];
    const float* projw = (const float*)d_in[5];
    const float* projb = (const float*)d_in[6];
    const float* ls1   = (const float*)d_in[7];
    const float* n2g   = (const float*)d_in[8];
    const float* n2b   = (const float*)d_in[9];
    const float* fc1w  = (const float*)d_in[10];
    const float* fc1b  = (const float*)d_in[11];
    const float* fc2w  = (const float*)d_in[12];
    const float* fc2b  = (const float*)d_in[13];
    const float* ls2   = (const float*)d_in[14];
    float* out = (float*)d_out;

    char* ws = (char*)d_ws;
    bf16_t* ln1p   = (bf16_t*)(ws);                 // 81920*256 bf16
    bf16_t* qkv    = (bf16_t*)(ws + 41943040ull);   // 81920*768 bf16
    bf16_t* ln2    = (bf16_t*)(ws + 167772160ull);  // 81920*256 bf16
    bf16_t* wbuf   = (bf16_t*)(ws + 209715200ull);  // weights ~1.5MB
    bf16_t* qkvwt  = wbuf;                          // [768][256]
    bf16_t* projwt = qkvwt + 768 * 256;             // [256][256]
    bf16_t* fc1wt  = projwt + 256 * 256;            // [1024][256]
    bf16_t* fc2wt  = fc1wt + 1024 * 256;            // [256][1024]
    bf16_t* attno  = ln1p;                          // overlay

    wconv_k<<<768,  256, 0, stream>>>(qkvw,  qkvwt, 768, 256);
    wconv_k<<<256,  256, 0, stream>>>(projw, projwt, 256, 256);
    wconv_k<<<1024, 256, 0, stream>>>(fc1w,  fc1wt, 1024, 256);
    wconv_k<<<1024, 256, 0, stream>>>(fc2w,  fc2wt, 256, 1024);

    ln_k<1><<<20480, 256, 0, stream>>>(x, n1g, n1b, ln1p);
    gemm_qkv_k<<<dim3(6, 640), 256, 0, stream>>>(ln1p, qkvwt, qkvb, qkv, 768, 256);
    attn_k<<<1024, 256, 0, stream>>>(qkv, attno);
    gemm_proj_k<<<dim3(2, 640), 256, 0, stream>>>(attno, projwt, projb, x, ls1, out, 256, 256);
    ln_k<0><<<20480, 256, 0, stream>>>(out, n2g, n2b, ln2);
    mlp_k<<<1280, 256, 0, stream>>>(ln2, fc1wt, fc1b, fc2wt, fc2b, ls2, out);
}